// Round 1
// baseline (1752.553 us; speedup 1.0000x reference)
//
#include <hip/hip_runtime.h>
#include <hip/hip_bf16.h>

#define DEV __device__ __forceinline__

typedef __attribute__((ext_vector_type(8))) short short8;
typedef __attribute__((ext_vector_type(4))) float floatx4;

DEV short f2bf(float f) {
  unsigned u = __float_as_uint(f);
  u += 0x7fffu + ((u >> 16) & 1u);
  return (short)(u >> 16);
}
DEV float bf2f(short s) {
  return __uint_as_float(((unsigned)(unsigned short)s) << 16);
}
DEV float wred(float v) {
#pragma unroll
  for (int m = 1; m < 64; m <<= 1) v += __shfl_xor(v, m);
  return v;
}
DEV floatx4 mfma16(short8 a, short8 b, floatx4 c) {
  return __builtin_amdgcn_mfma_f32_16x16x32_bf16(a, b, c, 0, 0, 0);
}

// ---------------------------------------------------------------------------
// Weight transpose+convert: src fp32 [K,N] -> dst bf16 [N][K]
// ---------------------------------------------------------------------------
struct MatDesc { const float* src; int K; int N; int off; };
struct MatTable { MatDesc m[35]; };

__global__ __launch_bounds__(256) void wtrans_kernel(MatTable T, short* __restrict__ dst) {
  int mi = blockIdx.y;
  MatDesc d = T.m[mi];
  int tilesx = d.N >> 5, tilesy = d.K >> 5;
  int tb = blockIdx.x;
  if (tb >= tilesx * tilesy) return;
  int ty = tb / tilesx, tx = tb % tilesx;
  __shared__ float tile[32][33];
  int tid = threadIdx.x;
#pragma unroll
  for (int i = 0; i < 4; ++i) {
    int e = tid + i * 256, lr = e >> 5, lc = e & 31;
    tile[lr][lc] = d.src[(size_t)(ty * 32 + lr) * d.N + tx * 32 + lc];
  }
  __syncthreads();
#pragma unroll
  for (int i = 0; i < 4; ++i) {
    int e = tid + i * 256, lr = e >> 5, lc = e & 31;
    dst[(size_t)d.off + (size_t)(tx * 32 + lr) * d.K + ty * 32 + lc] = f2bf(tile[lc][lr]);
  }
}

// ---------------------------------------------------------------------------
// Fused NeRF encode + positional/input embedding + LN(k), LN(v) -> bf16
// One wave per (b,n) row; 32 rows per block. W_pos staged transposed in LDS.
// ---------------------------------------------------------------------------
__global__ __launch_bounds__(256) void embed_kernel(
    const float* __restrict__ pos, const float* __restrict__ x,
    const float* __restrict__ W_pos, const float* __restrict__ b_pos,
    const float* __restrict__ W_in, const float* __restrict__ b_in,
    const float* __restrict__ lnk_g, const float* __restrict__ lnk_b,
    const float* __restrict__ lnv_g, const float* __restrict__ lnv_b,
    short* __restrict__ kn, short* __restrict__ vn) {
  __shared__ short wlds[512 * 56];  // [col 512][k 48 pad 56] bf16
  int tid = threadIdx.x;
  for (int e = tid; e < 48 * 512; e += 256) {
    int k = e >> 9, c = e & 511;
    wlds[c * 56 + k] = f2bf(W_pos[e]);
  }
  __syncthreads();
  int lane = tid & 63, wv = tid >> 6;
  int rb = blockIdx.x * 32;
  for (int rg = 0; rg < 8; ++rg) {
    int row = rb + rg * 4 + wv;  // 0..32767 = b*4096+n
    float p0 = pos[row * 2], p1 = pos[row * 2 + 1];
    float x0 = x[row * 3], x1 = x[row * 3 + 1], x2 = x[row * 3 + 2];
    float enc[48];
#pragma unroll
    for (int f = 0; f < 12; ++f) {
      float fr = exp2f((4.0f / 11.0f) * (float)f);
      float a0 = p0 * fr, a1 = p1 * fr;
      enc[f] = __sinf(a0); enc[12 + f] = __cosf(a0);
      enc[24 + f] = __sinf(a1); enc[36 + f] = __cosf(a1);
    }
    float kin[8], vin[8];
    float s1 = 0, q1 = 0, s2 = 0, q2 = 0;
#pragma unroll
    for (int j = 0; j < 8; ++j) {
      int c = lane + 64 * j;
      float acc = b_pos[c];
#pragma unroll
      for (int k6 = 0; k6 < 6; ++k6) {
        short8 w8 = *(const short8*)&wlds[c * 56 + k6 * 8];
#pragma unroll
        for (int jj = 0; jj < 8; ++jj) acc += bf2f(w8[jj]) * enc[k6 * 8 + jj];
      }
      float kk = fmaxf(acc, 0.f);
      float vv = x0 * W_in[c] + x1 * W_in[512 + c] + x2 * W_in[1024 + c] + b_in[c] + kk;
      kin[j] = kk; vin[j] = vv;
      s1 += kk; q1 += kk * kk; s2 += vv; q2 += vv * vv;
    }
    s1 = wred(s1); q1 = wred(q1); s2 = wred(s2); q2 = wred(q2);
    float m1 = s1 * (1.f / 512.f), v1 = q1 * (1.f / 512.f) - m1 * m1;
    float m2 = s2 * (1.f / 512.f), v2 = q2 * (1.f / 512.f) - m2 * m2;
    float r1 = rsqrtf(v1 + 1e-5f), r2 = rsqrtf(v2 + 1e-5f);
#pragma unroll
    for (int j = 0; j < 8; ++j) {
      int c = lane + 64 * j;
      kn[(size_t)row * 512 + c] = f2bf((kin[j] - m1) * r1 * lnk_g[c] + lnk_b[c]);
      vn[(size_t)row * 512 + c] = f2bf((vin[j] - m2) * r2 * lnv_g[c] + lnv_b[c]);
    }
  }
}

// ---------------------------------------------------------------------------
// LayerNorm fp32 in [M,512] -> bf16 out, one wave per row
// ---------------------------------------------------------------------------
__global__ __launch_bounds__(256) void ln_kernel(
    const float* __restrict__ in, const float* __restrict__ g,
    const float* __restrict__ b, short* __restrict__ out, int M) {
  int row = blockIdx.x * 4 + (threadIdx.x >> 6);
  if (row >= M) return;
  int lane = threadIdx.x & 63;
  float v[8]; float s = 0, q = 0;
#pragma unroll
  for (int j = 0; j < 8; ++j) {
    v[j] = in[(size_t)row * 512 + lane + 64 * j];
    s += v[j]; q += v[j] * v[j];
  }
  s = wred(s); q = wred(q);
  float m = s * (1.f / 512.f);
  float var = q * (1.f / 512.f) - m * m;
  float rs = rsqrtf(var + 1e-5f);
#pragma unroll
  for (int j = 0; j < 8; ++j) {
    int cc = lane + 64 * j;
    out[(size_t)row * 512 + cc] = f2bf((v[j] - m) * rs * g[cc] + b[cc]);
  }
}

// broadcast latents [256,512] -> lat [2048,512] fp32
__global__ void bcast_kernel(const float* __restrict__ latents, float* __restrict__ lat) {
  int i = blockIdx.x * 256 + threadIdx.x;
  lat[i] = latents[i & 131071];
}

// ---------------------------------------------------------------------------
// GEMM: out[M,N] = epi(A_bf16[M,K] @ W, +bias). W given transposed bf16 [N][K].
// 128x128 tile, BK=64, 4 waves (2x2), 16x16x32 MFMA.
// EPI: 0 = bf16 out, 1 = gelu->bf16, 2 = fp32 residual +=, 3 = fp32 out
// ---------------------------------------------------------------------------
template <int EPI>
__global__ __launch_bounds__(256) void gemm_kernel(
    const short* __restrict__ A, const short* __restrict__ Wt,
    const float* __restrict__ bias, void* __restrict__ outp,
    int M, int N, int K) {
  __shared__ short Alds[128 * 72];
  __shared__ short Blds[128 * 72];
  int tid = threadIdx.x;
  int brow = blockIdx.y * 128, bcol = blockIdx.x * 128;
  int lane = tid & 63, wvid = tid >> 6;
  int wr = wvid >> 1, wc = wvid & 1;
  int g = lane >> 4, c = lane & 15;
  floatx4 zf = {0.f, 0.f, 0.f, 0.f};
  floatx4 acc[4][4];
#pragma unroll
  for (int i = 0; i < 4; ++i)
#pragma unroll
    for (int j = 0; j < 4; ++j) acc[i][j] = zf;
  short8 z8 = {0, 0, 0, 0, 0, 0, 0, 0};

  for (int k0 = 0; k0 < K; k0 += 64) {
#pragma unroll
    for (int i = 0; i < 4; ++i) {
      int ch = tid + i * 256;
      int row = ch >> 3, k8 = (ch & 7) * 8;
      short8 av = *(const short8*)&A[(size_t)(brow + row) * K + k0 + k8];
      *(short8*)&Alds[row * 72 + k8] = av;
      int colg = bcol + row;
      short8 bv = z8;
      if (colg < N) bv = *(const short8*)&Wt[(size_t)colg * K + k0 + k8];
      *(short8*)&Blds[row * 72 + k8] = bv;
    }
    __syncthreads();
#pragma unroll
    for (int ks = 0; ks < 2; ++ks) {
      short8 af[4], bf8[4];
#pragma unroll
      for (int mf = 0; mf < 4; ++mf)
        af[mf] = *(const short8*)&Alds[(wr * 64 + mf * 16 + c) * 72 + ks * 32 + g * 8];
#pragma unroll
      for (int nf = 0; nf < 4; ++nf)
        bf8[nf] = *(const short8*)&Blds[(wc * 64 + nf * 16 + c) * 72 + ks * 32 + g * 8];
#pragma unroll
      for (int mf = 0; mf < 4; ++mf)
#pragma unroll
        for (int nf = 0; nf < 4; ++nf)
          acc[mf][nf] = mfma16(af[mf], bf8[nf], acc[mf][nf]);
    }
    __syncthreads();
  }

#pragma unroll
  for (int mf = 0; mf < 4; ++mf) {
#pragma unroll
    for (int nf = 0; nf < 4; ++nf) {
      int col = bcol + wc * 64 + nf * 16 + c;
      if (col >= N) continue;
      float bv = bias ? bias[col] : 0.f;
      int row0 = brow + wr * 64 + mf * 16 + g * 4;
#pragma unroll
      for (int r = 0; r < 4; ++r) {
        float xv = acc[mf][nf][r] + bv;
        size_t idx = (size_t)(row0 + r) * N + col;
        if (EPI == 0) {
          ((short*)outp)[idx] = f2bf(xv);
        } else if (EPI == 1) {
          float t = 0.7978845608f * (xv + 0.044715f * xv * xv * xv);
          ((short*)outp)[idx] = f2bf(0.5f * xv * (1.f + tanhf(t)));
        } else if (EPI == 2) {
          ((float*)outp)[idx] += xv;
        } else {
          ((float*)outp)[idx] = xv;
        }
      }
    }
  }
}

// ---------------------------------------------------------------------------
// Flash attention: one block = (qtile of 64 rows, head, batch). 4 waves, each
// wave owns 16 q rows. K tiles of 64 tokens, online softmax, P via LDS.
// q bf16 [.,512] col h*64+d ; k/v bf16 rows with stride kvrstride.
// ---------------------------------------------------------------------------
__global__ __launch_bounds__(256) void flash_kernel(
    const short* __restrict__ q, const short* __restrict__ k,
    const short* __restrict__ v, short* __restrict__ out,
    int qbstride, long kvbstride, int kvrstride, int nkv) {
  __shared__ short Qs[64 * 72];
  __shared__ short Ks[64 * 72];
  __shared__ short Vt[64 * 72];
  __shared__ short Ps[64 * 72];
  int tid = threadIdx.x;
  int b = blockIdx.z, h = blockIdx.y, qt = blockIdx.x;
  int lane = tid & 63, wv = tid >> 6;
  int g = lane >> 4, c = lane & 15;

  for (int ch = tid; ch < 512; ch += 256) {
    int j = ch >> 3, f0 = (ch & 7) * 8;
    short8 t = *(const short8*)&q[((size_t)(b * qbstride) + qt * 64 + j) * 512 + h * 64 + f0];
    *(short8*)&Qs[j * 72 + f0] = t;
  }

  float m_[4], l_[4];
  floatx4 zf = {0.f, 0.f, 0.f, 0.f};
  floatx4 o_[4];
#pragma unroll
  for (int r = 0; r < 4; ++r) { m_[r] = -3.0e38f; l_[r] = 0.f; }
#pragma unroll
  for (int f = 0; f < 4; ++f) o_[f] = zf;

  for (int t0 = 0; t0 < nkv; t0 += 64) {
    for (int ch = tid; ch < 512; ch += 256) {
      int j = ch >> 3, f0 = (ch & 7) * 8;
      long roff = (long)b * kvbstride + (long)(t0 + j) * kvrstride + h * 64 + f0;
      short8 tk = *(const short8*)&k[roff];
      *(short8*)&Ks[j * 72 + f0] = tk;
      short8 tv = *(const short8*)&v[roff];
#pragma unroll
      for (int jj = 0; jj < 8; ++jj) Vt[(f0 + jj) * 72 + j] = tv[jj];
    }
    __syncthreads();

    floatx4 s[4];
#pragma unroll
    for (int f = 0; f < 4; ++f) s[f] = zf;
#pragma unroll
    for (int ks = 0; ks < 2; ++ks) {
      short8 a = *(const short8*)&Qs[(wv * 16 + c) * 72 + ks * 32 + g * 8];
#pragma unroll
      for (int f = 0; f < 4; ++f) {
        short8 b8 = *(const short8*)&Ks[(f * 16 + c) * 72 + ks * 32 + g * 8];
        s[f] = mfma16(a, b8, s[f]);
      }
    }
#pragma unroll
    for (int f = 0; f < 4; ++f)
#pragma unroll
      for (int r = 0; r < 4; ++r) s[f][r] *= 0.125f;

    float nm[4], sf[4], rs[4];
#pragma unroll
    for (int r = 0; r < 4; ++r) {
      float t = fmaxf(fmaxf(s[0][r], s[1][r]), fmaxf(s[2][r], s[3][r]));
#pragma unroll
      for (int msk = 1; msk < 16; msk <<= 1) t = fmaxf(t, __shfl_xor(t, msk));
      nm[r] = fmaxf(m_[r], t);
      sf[r] = __expf(m_[r] - nm[r]);
      rs[r] = 0.f;
    }
#pragma unroll
    for (int f = 0; f < 4; ++f)
#pragma unroll
      for (int r = 0; r < 4; ++r) {
        float p = __expf(s[f][r] - nm[r]);
        s[f][r] = p; rs[r] += p;
      }
#pragma unroll
    for (int r = 0; r < 4; ++r) {
#pragma unroll
      for (int msk = 1; msk < 16; msk <<= 1) rs[r] += __shfl_xor(rs[r], msk);
      l_[r] = l_[r] * sf[r] + rs[r];
      m_[r] = nm[r];
    }
#pragma unroll
    for (int f = 0; f < 4; ++f)
#pragma unroll
      for (int r = 0; r < 4; ++r) o_[f][r] *= sf[r];
#pragma unroll
    for (int f = 0; f < 4; ++f)
#pragma unroll
      for (int r = 0; r < 4; ++r)
        Ps[(wv * 16 + g * 4 + r) * 72 + f * 16 + c] = f2bf(s[f][r]);
    __syncthreads();
#pragma unroll
    for (int ks = 0; ks < 2; ++ks) {
      short8 pa = *(const short8*)&Ps[(wv * 16 + c) * 72 + ks * 32 + g * 8];
#pragma unroll
      for (int f = 0; f < 4; ++f) {
        short8 vb = *(const short8*)&Vt[(f * 16 + c) * 72 + ks * 32 + g * 8];
        o_[f] = mfma16(pa, vb, o_[f]);
      }
    }
    __syncthreads();
  }

#pragma unroll
  for (int f = 0; f < 4; ++f)
#pragma unroll
    for (int r = 0; r < 4; ++r) {
      int row = qt * 64 + wv * 16 + g * 4 + r;
      float val = o_[f][r] / l_[r];
      out[((size_t)(b * 256 + row)) * 512 + h * 64 + f * 16 + c] = f2bf(val);
    }
}

// ---------------------------------------------------------------------------
extern "C" void kernel_launch(void* const* d_in, const int* in_sizes, int n_in,
                              void* d_out, int out_size, void* d_ws, size_t ws_size,
                              hipStream_t stream) {
  const float* x       = (const float*)d_in[0];
  const float* pos     = (const float*)d_in[1];
  const float* W_pos   = (const float*)d_in[2];
  const float* b_pos   = (const float*)d_in[3];
  const float* W_in    = (const float*)d_in[4];
  const float* b_in    = (const float*)d_in[5];
  const float* latents = (const float*)d_in[6];
  const float* lnq_g   = (const float*)d_in[7];
  const float* lnq_b   = (const float*)d_in[8];
  const float* lnk_g   = (const float*)d_in[9];
  const float* lnk_b   = (const float*)d_in[10];
  const float* lnv_g   = (const float*)d_in[11];
  const float* lnv_b   = (const float*)d_in[12];
  const float* cWq     = (const float*)d_in[13];
  const float* cWk     = (const float*)d_in[14];
  const float* cWv     = (const float*)d_in[15];
  const float* cWo     = (const float*)d_in[16];
  const float* c_bo    = (const float*)d_in[17];
  const float* ln1_g   = (const float*)d_in[18];
  const float* ln1_b   = (const float*)d_in[19];
  const float* sWq     = (const float*)d_in[20];
  const float* sWkv    = (const float*)d_in[21];
  const float* sWo     = (const float*)d_in[22];
  const float* s_bo    = (const float*)d_in[23];
  const float* ln2_g   = (const float*)d_in[24];
  const float* ln2_b   = (const float*)d_in[25];
  const float* fW1     = (const float*)d_in[26];
  const float* f_b1    = (const float*)d_in[27];
  const float* fW2     = (const float*)d_in[28];
  const float* f_b2    = (const float*)d_in[29];
  const float* lnf_g   = (const float*)d_in[30];
  const float* lnf_b   = (const float*)d_in[31];
  const float* Wb      = (const float*)d_in[32];
  const float* bbv     = (const float*)d_in[33];
  float* outp = (float*)d_out;

  // bf16 transposed weight offsets (elements)
  size_t W = 0;
  size_t o_cWq = W; W += 512 * 512;
  size_t o_cWk = W; W += 512 * 512;
  size_t o_cWv = W; W += 512 * 512;
  size_t o_cWo = W; W += 512 * 512;
  size_t o_Wb  = W; W += 64 * 512;
  size_t o_sWq[6], o_sWkv[6], o_sWo[6], o_fW1[6], o_fW2[6];
  for (int i = 0; i < 6; ++i) {
    o_sWq[i]  = W; W += 512 * 512;
    o_sWkv[i] = W; W += 1024 * 512;
    o_sWo[i]  = W; W += 512 * 512;
    o_fW1[i]  = W; W += 2048 * 512;
    o_fW2[i]  = W; W += 512 * 2048;
  }
  MatTable T;
  int nm = 0;
  auto add = [&](const float* s, int K, int N, size_t off) {
    T.m[nm].src = s; T.m[nm].K = K; T.m[nm].N = N; T.m[nm].off = (int)off; ++nm;
  };
  add(cWq, 512, 512, o_cWq); add(cWk, 512, 512, o_cWk);
  add(cWv, 512, 512, o_cWv); add(cWo, 512, 512, o_cWo);
  add(Wb, 512, 64, o_Wb);
  for (int i = 0; i < 6; ++i) {
    add(sWq  + (size_t)i * 512 * 512,  512, 512,  o_sWq[i]);
    add(sWkv + (size_t)i * 512 * 1024, 512, 1024, o_sWkv[i]);
    add(sWo  + (size_t)i * 512 * 512,  512, 512,  o_sWo[i]);
    add(fW1  + (size_t)i * 512 * 2048, 512, 2048, o_fW1[i]);
    add(fW2  + (size_t)i * 2048 * 512, 2048, 512, o_fW2[i]);
  }

  // workspace carve
  char* p = (char*)d_ws;
  auto carve = [&](size_t bytes) {
    char* r = p; p += (bytes + 255) & ~(size_t)255; return r;
  };
  short* wtb   = (short*)carve(W * 2);
  short* kn    = (short*)carve(33554432);
  short* vn    = (short*)carve(33554432);
  short* kproj = (short*)carve(33554432);
  short* vproj = (short*)carve(33554432);
  short* latn0 = (short*)carve(262144);
  short* qc    = (short*)carve(262144);
  float* lat   = (float*)carve(4194304);
  // aliases into dead regions
  short* attno = kn;                                  // kn dead after kproj GEMM
  short* h     = vn;                                  // vn dead after vproj GEMM
  short* qs    = (short*)((char*)vn + 2097152);
  short* kvb   = (short*)((char*)vn + 4194304);
  short* ffh   = (short*)((char*)vn + 8388608);

  wtrans_kernel<<<dim3(1024, 35), 256, 0, stream>>>(T, wtb);
  embed_kernel<<<1024, 256, 0, stream>>>(pos, x, W_pos, b_pos, W_in, b_in,
                                         lnk_g, lnk_b, lnv_g, lnv_b, kn, vn);
  bcast_kernel<<<4096, 256, 0, stream>>>(latents, lat);
  ln_kernel<<<64, 256, 0, stream>>>(latents, lnq_g, lnq_b, latn0, 256);
  gemm_kernel<0><<<dim3(4, 2), 256, 0, stream>>>(latn0, wtb + o_cWq, nullptr, qc, 256, 512, 512);
  gemm_kernel<0><<<dim3(4, 256), 256, 0, stream>>>(kn, wtb + o_cWk, nullptr, kproj, 32768, 512, 512);
  gemm_kernel<0><<<dim3(4, 256), 256, 0, stream>>>(vn, wtb + o_cWv, nullptr, vproj, 32768, 512, 512);
  flash_kernel<<<dim3(4, 8, 8), 256, 0, stream>>>(qc, kproj, vproj, attno,
                                                  0, (long)4096 * 512, 512, 4096);
  gemm_kernel<2><<<dim3(4, 16), 256, 0, stream>>>(attno, wtb + o_cWo, c_bo, lat, 2048, 512, 512);

  for (int i = 0; i < 6; ++i) {
    ln_kernel<<<512, 256, 0, stream>>>(lat, ln1_g + i * 512, ln1_b + i * 512, h, 2048);
    gemm_kernel<0><<<dim3(4, 16), 256, 0, stream>>>(h, wtb + o_sWq[i], nullptr, qs, 2048, 512, 512);
    gemm_kernel<0><<<dim3(8, 16), 256, 0, stream>>>(h, wtb + o_sWkv[i], nullptr, kvb, 2048, 1024, 512);
    flash_kernel<<<dim3(4, 8, 8), 256, 0, stream>>>(qs, kvb, kvb + 512, attno,
                                                    256, (long)256 * 1024, 1024, 256);
    gemm_kernel<2><<<dim3(4, 16), 256, 0, stream>>>(attno, wtb + o_sWo[i], s_bo + i * 512, lat, 2048, 512, 512);
    ln_kernel<<<512, 256, 0, stream>>>(lat, ln2_g + i * 512, ln2_b + i * 512, h, 2048);
    gemm_kernel<1><<<dim3(16, 16), 256, 0, stream>>>(h, wtb + o_fW1[i], f_b1 + i * 2048, ffh, 2048, 2048, 512);
    gemm_kernel<2><<<dim3(4, 16), 256, 0, stream>>>(ffh, wtb + o_fW2[i], f_b2 + i * 512, lat, 2048, 512, 2048);
  }
  ln_kernel<<<512, 256, 0, stream>>>(lat, lnf_g, lnf_b, h, 2048);
  gemm_kernel<3><<<dim3(1, 16), 256, 0, stream>>>(h, wtb + o_Wb, bbv, outp, 2048, 64, 512);
}

// Round 2
// 888.758 us; speedup vs baseline: 1.9719x; 1.9719x over previous
//
#include <hip/hip_runtime.h>
#include <hip/hip_bf16.h>

#define DEV __device__ __forceinline__

typedef __attribute__((ext_vector_type(8))) short short8;
typedef __attribute__((ext_vector_type(4))) float floatx4;

DEV short f2bf(float f) {
  unsigned u = __float_as_uint(f);
  u += 0x7fffu + ((u >> 16) & 1u);
  return (short)(u >> 16);
}
DEV float bf2f(short s) {
  return __uint_as_float(((unsigned)(unsigned short)s) << 16);
}
DEV float wred(float v) {
#pragma unroll
  for (int m = 1; m < 64; m <<= 1) v += __shfl_xor(v, m);
  return v;
}
DEV floatx4 mfma16(short8 a, short8 b, floatx4 c) {
  return __builtin_amdgcn_mfma_f32_16x16x32_bf16(a, b, c, 0, 0, 0);
}
// async global->LDS, 16B per lane, dest = wave-uniform base + lane*16
DEV void gload16(void* lds, const void* g) {
  __builtin_amdgcn_global_load_lds(
      (const __attribute__((address_space(1))) unsigned int*)g,
      (__attribute__((address_space(3))) unsigned int*)lds, 16, 0, 0);
}

// ---------------------------------------------------------------------------
// Weight transpose+convert: src fp32 [K,N] -> dst bf16 [N][kp] (zero pad K..kp)
// ---------------------------------------------------------------------------
struct MatDesc { const float* src; int K; int N; int kp; int off; };
struct MatTable { MatDesc m[36]; };

__global__ __launch_bounds__(256) void wtrans_kernel(MatTable T, short* __restrict__ dst) {
  int mi = blockIdx.y;
  MatDesc d = T.m[mi];
  int tilesx = d.N >> 5, tilesy = d.kp >> 5;
  int tb = blockIdx.x;
  if (tb >= tilesx * tilesy) return;
  int ty = tb / tilesx, tx = tb % tilesx;
  __shared__ float tile[32][33];
  int tid = threadIdx.x;
#pragma unroll
  for (int i = 0; i < 4; ++i) {
    int e = tid + i * 256, lr = e >> 5, lc = e & 31;
    int kk = ty * 32 + lr;
    tile[lr][lc] = (kk < d.K) ? d.src[(size_t)kk * d.N + tx * 32 + lc] : 0.f;
  }
  __syncthreads();
#pragma unroll
  for (int i = 0; i < 4; ++i) {
    int e = tid + i * 256, lr = e >> 5, lc = e & 31;
    dst[(size_t)d.off + (size_t)(tx * 32 + lr) * d.kp + ty * 32 + lc] = f2bf(tile[lc][lr]);
  }
}

// ---------------------------------------------------------------------------
// NeRF encode -> enc bf16 [32768, 64] (k 48..63 = 0)
// ---------------------------------------------------------------------------
__global__ __launch_bounds__(256) void enc_kernel(const float* __restrict__ pos,
                                                  short* __restrict__ enc) {
  int idx = blockIdx.x * 256 + threadIdx.x;
  int row = idx >> 3, oct = idx & 7;
  float p0 = pos[row * 2], p1 = pos[row * 2 + 1];
  short8 o;
#pragma unroll
  for (int j = 0; j < 8; ++j) {
    int k = oct * 8 + j;
    float val = 0.f;
    if (k < 48) {
      int dd = k / 24, rem = k % 24;
      int trig = rem / 12, f = rem % 12;
      float ang = (dd ? p1 : p0) * exp2f((4.0f / 11.0f) * (float)f);
      val = trig ? __cosf(ang) : __sinf(ang);
    }
    o[j] = f2bf(val);
  }
  *(short8*)&enc[(size_t)row * 64 + oct * 8] = o;
}

// ---------------------------------------------------------------------------
// Fused pos-embed GEMM (enc @ W_pos^T, K=64) + relu + x@W_in + LN(k), LN(v)
// 512 threads = 8 waves; block = 128 rows; wave = 16 rows x 512 cols.
// ---------------------------------------------------------------------------
__global__ __launch_bounds__(512) void embed2_kernel(
    const short* __restrict__ enc, const short* __restrict__ Wt,  // [512][64]
    const float* __restrict__ b_pos, const float* __restrict__ W_in,
    const float* __restrict__ b_in, const float* __restrict__ x,
    const float* __restrict__ lnk_g, const float* __restrict__ lnk_b,
    const float* __restrict__ lnv_g, const float* __restrict__ lnv_b,
    short* __restrict__ kn, short* __restrict__ vn) {
  __shared__ short Wl[512 * 64];
  __shared__ short El[128 * 64];
  int tid = threadIdx.x;
  int lane = tid & 63, wv = tid >> 6;
  int c = lane & 15, g = lane >> 4;
  int blk = blockIdx.x * 128;
  // stage W_pos^T: 64 groups of 8 rows, 8 per wave
#pragma unroll
  for (int gi = 0; gi < 8; ++gi) {
    int grp = wv * 8 + gi;
    int row = grp * 8 + (lane >> 3), kc = lane & 7;
    gload16(&Wl[grp * 512], &Wt[(size_t)row * 64 + ((kc ^ (row & 7)) * 8)]);
  }
  // stage enc rows: 16 groups, 2 per wave
#pragma unroll
  for (int gi = 0; gi < 2; ++gi) {
    int grp = wv * 2 + gi;
    int row = grp * 8 + (lane >> 3), kc = lane & 7;
    gload16(&El[grp * 512], &enc[(size_t)(blk + row) * 64 + ((kc ^ (row & 7)) * 8)]);
  }
  __syncthreads();

  floatx4 acc[32];
  floatx4 zf = {0.f, 0.f, 0.f, 0.f};
#pragma unroll
  for (int nf = 0; nf < 32; ++nf) acc[nf] = zf;
  short8 af[2];
#pragma unroll
  for (int ks = 0; ks < 2; ++ks)
    af[ks] = *(const short8*)&El[(wv * 16 + c) * 64 + ((ks * 4 + g) ^ (c & 7)) * 8];
#pragma unroll
  for (int nf = 0; nf < 32; ++nf) {
#pragma unroll
    for (int ks = 0; ks < 2; ++ks) {
      short8 bf8 = *(const short8*)&Wl[(nf * 16 + c) * 64 + ((ks * 4 + g) ^ (c & 7)) * 8];
      acc[nf] = mfma16(af[ks], bf8, acc[nf]);
    }
  }

  // epilogue: per lane 4 rows x 32 cols
  int rowbase = blk + wv * 16 + g * 4;
  float x0[4], x1[4], x2[4];
  float s1[4], q1[4], s2[4], q2[4];
#pragma unroll
  for (int r = 0; r < 4; ++r) {
    x0[r] = x[(size_t)(rowbase + r) * 3];
    x1[r] = x[(size_t)(rowbase + r) * 3 + 1];
    x2[r] = x[(size_t)(rowbase + r) * 3 + 2];
    s1[r] = 0; q1[r] = 0; s2[r] = 0; q2[r] = 0;
  }
#pragma unroll
  for (int nf = 0; nf < 32; ++nf) {
    int col = nf * 16 + c;
    float bp = b_pos[col];
    float w0 = W_in[col], w1 = W_in[512 + col], w2 = W_in[1024 + col], bi = b_in[col];
#pragma unroll
    for (int r = 0; r < 4; ++r) {
      float kk = fmaxf(acc[nf][r] + bp, 0.f);
      float vv = kk + x0[r] * w0 + x1[r] * w1 + x2[r] * w2 + bi;
      acc[nf][r] = kk;
      s1[r] += kk; q1[r] += kk * kk; s2[r] += vv; q2[r] += vv * vv;
    }
  }
  float m1[4], r1[4], m2[4], r2[4];
#pragma unroll
  for (int r = 0; r < 4; ++r) {
#pragma unroll
    for (int msk = 1; msk < 16; msk <<= 1) {
      s1[r] += __shfl_xor(s1[r], msk); q1[r] += __shfl_xor(q1[r], msk);
      s2[r] += __shfl_xor(s2[r], msk); q2[r] += __shfl_xor(q2[r], msk);
    }
    m1[r] = s1[r] * (1.f / 512.f);
    r1[r] = rsqrtf(q1[r] * (1.f / 512.f) - m1[r] * m1[r] + 1e-5f);
    m2[r] = s2[r] * (1.f / 512.f);
    r2[r] = rsqrtf(q2[r] * (1.f / 512.f) - m2[r] * m2[r] + 1e-5f);
  }
#pragma unroll
  for (int nf = 0; nf < 32; ++nf) {
    int col = nf * 16 + c;
    float w0 = W_in[col], w1 = W_in[512 + col], w2 = W_in[1024 + col], bi = b_in[col];
    float gk = lnk_g[col], bk = lnk_b[col], gv = lnv_g[col], bv = lnv_b[col];
#pragma unroll
    for (int r = 0; r < 4; ++r) {
      float kk = acc[nf][r];
      float vv = kk + x0[r] * w0 + x1[r] * w1 + x2[r] * w2 + bi;
      size_t idx = (size_t)(rowbase + r) * 512 + col;
      kn[idx] = f2bf((kk - m1[r]) * r1[r] * gk + bk);
      vn[idx] = f2bf((vv - m2[r]) * r2[r] * gv + bv);
    }
  }
}

// ---------------------------------------------------------------------------
// LayerNorm fp32 in [M,512] -> bf16 out, one wave per row
// ---------------------------------------------------------------------------
__global__ __launch_bounds__(256) void ln_kernel(
    const float* __restrict__ in, const float* __restrict__ g,
    const float* __restrict__ b, short* __restrict__ out, int M) {
  int row = blockIdx.x * 4 + (threadIdx.x >> 6);
  if (row >= M) return;
  int lane = threadIdx.x & 63;
  float v[8]; float s = 0, q = 0;
#pragma unroll
  for (int j = 0; j < 8; ++j) {
    v[j] = in[(size_t)row * 512 + lane + 64 * j];
    s += v[j]; q += v[j] * v[j];
  }
  s = wred(s); q = wred(q);
  float m = s * (1.f / 512.f);
  float rs = rsqrtf(q * (1.f / 512.f) - m * m + 1e-5f);
#pragma unroll
  for (int j = 0; j < 8; ++j) {
    int cc = lane + 64 * j;
    out[(size_t)row * 512 + cc] = f2bf((v[j] - m) * rs * g[cc] + b[cc]);
  }
}

// broadcast latents [256,512] -> lat [2048,512] fp32
__global__ void bcast_kernel(const float* __restrict__ latents, float* __restrict__ lat) {
  int i = blockIdx.x * 256 + threadIdx.x;
  lat[i] = latents[i & 131071];
}

// ---------------------------------------------------------------------------
// Shared GEMM epilogue op
// EPI: 0 = bf16 out, 1 = gelu->bf16, 2 = fp32 residual +=, 3 = fp32 out
// ---------------------------------------------------------------------------
template <int EPI>
DEV void epi_store(void* outp, size_t idx, float xv) {
  if (EPI == 0) {
    ((short*)outp)[idx] = f2bf(xv);
  } else if (EPI == 1) {
    float t = 0.7978845608f * (xv + 0.044715f * xv * xv * xv);
    ((short*)outp)[idx] = f2bf(0.5f * xv * (1.f + tanhf(t)));
  } else if (EPI == 2) {
    ((float*)outp)[idx] += xv;
  } else {
    ((float*)outp)[idx] = xv;
  }
}

// ---------------------------------------------------------------------------
// GEMM 128x128 tile, BK=64, 4 waves (2x2). A bf16 [M,K]; Wt bf16 [N][K].
// global_load_lds staging, pre-swizzled source + swizzled ds_read.
// M % 128 == 0, N % 128 == 0.
// ---------------------------------------------------------------------------
template <int EPI>
__global__ __launch_bounds__(256) void gemm_kernel(
    const short* __restrict__ A, const short* __restrict__ Wt,
    const float* __restrict__ bias, void* __restrict__ outp,
    int M, int N, int K, int ldo) {
  __shared__ short Alds[128 * 64];
  __shared__ short Blds[128 * 64];
  int tid = threadIdx.x;
  int brow = blockIdx.y * 128, bcol = blockIdx.x * 128;
  int lane = tid & 63, wvid = tid >> 6;
  int wr = wvid >> 1, wc = wvid & 1;
  int g = lane >> 4, c = lane & 15;
  floatx4 zf = {0.f, 0.f, 0.f, 0.f};
  floatx4 acc[4][4];
#pragma unroll
  for (int i = 0; i < 4; ++i)
#pragma unroll
    for (int j = 0; j < 4; ++j) acc[i][j] = zf;

  int srow = (lane >> 3), skc = lane & 7;
  for (int k0 = 0; k0 < K; k0 += 64) {
#pragma unroll
    for (int gi = 0; gi < 4; ++gi) {
      int grp = wvid * 4 + gi;
      int row = grp * 8 + srow;
      int sw = ((skc ^ (row & 7)) * 8);
      gload16(&Alds[grp * 512], &A[(size_t)(brow + row) * K + k0 + sw]);
      gload16(&Blds[grp * 512], &Wt[(size_t)(bcol + row) * K + k0 + sw]);
    }
    __syncthreads();
#pragma unroll
    for (int ks = 0; ks < 2; ++ks) {
      int slot = ((ks * 4 + g) ^ (c & 7)) * 8;
      short8 af[4], bf8[4];
#pragma unroll
      for (int mf = 0; mf < 4; ++mf)
        af[mf] = *(const short8*)&Alds[(wr * 64 + mf * 16 + c) * 64 + slot];
#pragma unroll
      for (int nf = 0; nf < 4; ++nf)
        bf8[nf] = *(const short8*)&Blds[(wc * 64 + nf * 16 + c) * 64 + slot];
#pragma unroll
      for (int mf = 0; mf < 4; ++mf)
#pragma unroll
        for (int nf = 0; nf < 4; ++nf)
          acc[mf][nf] = mfma16(af[mf], bf8[nf], acc[mf][nf]);
    }
    __syncthreads();
  }

#pragma unroll
  for (int mf = 0; mf < 4; ++mf) {
#pragma unroll
    for (int nf = 0; nf < 4; ++nf) {
      int col = bcol + wc * 64 + nf * 16 + c;
      float bv = bias ? bias[col] : 0.f;
      int row0 = brow + wr * 64 + mf * 16 + g * 4;
#pragma unroll
      for (int r = 0; r < 4; ++r)
        epi_store<EPI>(outp, (size_t)(row0 + r) * ldo + col, acc[mf][nf][r] + bv);
    }
  }
}

// ---------------------------------------------------------------------------
// GEMM 64x64 tile for grid-starved (M=2048,N<=1536) cases. 4 waves (2x2),
// each wave 32x32. M % 64 == 0, N % 64 == 0.
// ---------------------------------------------------------------------------
template <int EPI>
__global__ __launch_bounds__(256) void gemm64_kernel(
    const short* __restrict__ A, const short* __restrict__ Wt,
    const float* __restrict__ bias, void* __restrict__ outp,
    int M, int N, int K, int ldo) {
  __shared__ short Alds[64 * 64];
  __shared__ short Blds[64 * 64];
  int tid = threadIdx.x;
  int brow = blockIdx.y * 64, bcol = blockIdx.x * 64;
  int lane = tid & 63, wvid = tid >> 6;
  int wr = wvid >> 1, wc = wvid & 1;
  int g = lane >> 4, c = lane & 15;
  floatx4 zf = {0.f, 0.f, 0.f, 0.f};
  floatx4 acc[2][2];
#pragma unroll
  for (int i = 0; i < 2; ++i)
#pragma unroll
    for (int j = 0; j < 2; ++j) acc[i][j] = zf;

  int srow = (lane >> 3), skc = lane & 7;
  for (int k0 = 0; k0 < K; k0 += 64) {
#pragma unroll
    for (int gi = 0; gi < 2; ++gi) {
      int grp = wvid * 2 + gi;
      int row = grp * 8 + srow;
      int sw = ((skc ^ (row & 7)) * 8);
      gload16(&Alds[grp * 512], &A[(size_t)(brow + row) * K + k0 + sw]);
      gload16(&Blds[grp * 512], &Wt[(size_t)(bcol + row) * K + k0 + sw]);
    }
    __syncthreads();
#pragma unroll
    for (int ks = 0; ks < 2; ++ks) {
      int slot = ((ks * 4 + g) ^ (c & 7)) * 8;
      short8 af[2], bf8[2];
#pragma unroll
      for (int mf = 0; mf < 2; ++mf)
        af[mf] = *(const short8*)&Alds[(wr * 32 + mf * 16 + c) * 64 + slot];
#pragma unroll
      for (int nf = 0; nf < 2; ++nf)
        bf8[nf] = *(const short8*)&Blds[(wc * 32 + nf * 16 + c) * 64 + slot];
#pragma unroll
      for (int mf = 0; mf < 2; ++mf)
#pragma unroll
        for (int nf = 0; nf < 2; ++nf)
          acc[mf][nf] = mfma16(af[mf], bf8[nf], acc[mf][nf]);
    }
    __syncthreads();
  }

#pragma unroll
  for (int mf = 0; mf < 2; ++mf) {
#pragma unroll
    for (int nf = 0; nf < 2; ++nf) {
      int col = bcol + wc * 32 + nf * 16 + c;
      float bv = bias ? bias[col] : 0.f;
      int row0 = brow + wr * 32 + mf * 16 + g * 4;
#pragma unroll
      for (int r = 0; r < 4; ++r)
        epi_store<EPI>(outp, (size_t)(row0 + r) * ldo + col, acc[mf][nf][r] + bv);
    }
  }
}

// ---------------------------------------------------------------------------
// Flash attention. Block = (qtile 64 rows, head, batch), 4 waves x 16 q rows.
// Q/K tiles via global_load_lds (swizzled); V via slot-swizzled scatter.
// ---------------------------------------------------------------------------
__global__ __launch_bounds__(256) void flash_kernel(
    const short* __restrict__ q, const short* __restrict__ k,
    const short* __restrict__ v, short* __restrict__ out,
    int qrs, int qbrows, long kvbstride, int kvrstride, int nkv) {
  __shared__ short Qs[64 * 64];
  __shared__ short Ks[64 * 64];
  __shared__ short Vt[64 * 72];
  __shared__ short Ps[64 * 72];
  int tid = threadIdx.x;
  int b = blockIdx.z, h = blockIdx.y, qt = blockIdx.x;
  int lane = tid & 63, wv = tid >> 6;
  int g = lane >> 4, c = lane & 15;
  int srow = lane >> 3, skc = lane & 7;

  // stage Q once
#pragma unroll
  for (int gi = 0; gi < 2; ++gi) {
    int grp = wv * 2 + gi;
    int row = grp * 8 + srow;
    int sw = ((skc ^ (row & 7)) * 8);
    gload16(&Qs[grp * 512],
            &q[((size_t)(b * qbrows) + qt * 64 + row) * qrs + h * 64 + sw]);
  }

  float m_[4], l_[4];
  floatx4 zf = {0.f, 0.f, 0.f, 0.f};
  floatx4 o_[4];
#pragma unroll
  for (int r = 0; r < 4; ++r) { m_[r] = -3.0e38f; l_[r] = 0.f; }
#pragma unroll
  for (int f = 0; f < 4; ++f) o_[f] = zf;

  for (int t0 = 0; t0 < nkv; t0 += 64) {
    // K tile via gload
#pragma unroll
    for (int gi = 0; gi < 2; ++gi) {
      int grp = wv * 2 + gi;
      int row = grp * 8 + srow;
      int sw = ((skc ^ (row & 7)) * 8);
      gload16(&Ks[grp * 512],
              &k[(size_t)b * kvbstride + (size_t)(t0 + row) * kvrstride + h * 64 + sw]);
    }
    // V tile, transposed scatter with slot swizzle
#pragma unroll
    for (int it = 0; it < 2; ++it) {
      int ch = tid + it * 256;
      int j = ch >> 3, f0 = (ch & 7) * 8, mm = ch & 7, tg = j >> 3;
      short8 tv = *(const short8*)&v[(size_t)b * kvbstride + (size_t)(t0 + j) * kvrstride + h * 64 + f0];
#pragma unroll
      for (int jj = 0; jj < 8; ++jj)
        Vt[(f0 + jj) * 72 + ((tg ^ mm) * 8) + (j & 7)] = tv[jj];
    }
    __syncthreads();

    floatx4 s[4];
#pragma unroll
    for (int f = 0; f < 4; ++f) s[f] = zf;
#pragma unroll
    for (int ks = 0; ks < 2; ++ks) {
      int slot = ((ks * 4 + g) ^ (c & 7)) * 8;
      short8 a = *(const short8*)&Qs[(wv * 16 + c) * 64 + slot];
#pragma unroll
      for (int f = 0; f < 4; ++f) {
        short8 b8 = *(const short8*)&Ks[(f * 16 + c) * 64 + slot];
        s[f] = mfma16(a, b8, s[f]);
      }
    }
#pragma unroll
    for (int f = 0; f < 4; ++f)
#pragma unroll
      for (int r = 0; r < 4; ++r) s[f][r] *= 0.125f;

    float nm[4], sf[4], rs[4];
#pragma unroll
    for (int r = 0; r < 4; ++r) {
      float t = fmaxf(fmaxf(s[0][r], s[1][r]), fmaxf(s[2][r], s[3][r]));
#pragma unroll
      for (int msk = 1; msk < 16; msk <<= 1) t = fmaxf(t, __shfl_xor(t, msk));
      nm[r] = fmaxf(m_[r], t);
      sf[r] = __expf(m_[r] - nm[r]);
      rs[r] = 0.f;
    }
#pragma unroll
    for (int f = 0; f < 4; ++f)
#pragma unroll
      for (int r = 0; r < 4; ++r) {
        float p = __expf(s[f][r] - nm[r]);
        s[f][r] = p; rs[r] += p;
      }
#pragma unroll
    for (int r = 0; r < 4; ++r) {
#pragma unroll
      for (int msk = 1; msk < 16; msk <<= 1) rs[r] += __shfl_xor(rs[r], msk);
      l_[r] = l_[r] * sf[r] + rs[r];
      m_[r] = nm[r];
    }
#pragma unroll
    for (int f = 0; f < 4; ++f)
#pragma unroll
      for (int r = 0; r < 4; ++r) o_[f][r] *= sf[r];
#pragma unroll
    for (int f = 0; f < 4; ++f)
#pragma unroll
      for (int r = 0; r < 4; ++r)
        Ps[(wv * 16 + g * 4 + r) * 72 + f * 16 + c] = f2bf(s[f][r]);
    __syncthreads();
#pragma unroll
    for (int ks = 0; ks < 2; ++ks) {
      short8 pa = *(const short8*)&Ps[(wv * 16 + c) * 72 + ks * 32 + g * 8];
#pragma unroll
      for (int f = 0; f < 4; ++f) {
        int mm = (2 * f + (c >> 3)) & 7;
        short8 vb = *(const short8*)&Vt[(f * 16 + c) * 72 + ((ks * 4 + g) ^ mm) * 8];
        o_[f] = mfma16(pa, vb, o_[f]);
      }
    }
    __syncthreads();
  }

#pragma unroll
  for (int f = 0; f < 4; ++f)
#pragma unroll
    for (int r = 0; r < 4; ++r) {
      int row = qt * 64 + wv * 16 + g * 4 + r;
      float val = o_[f][r] / l_[r];
      out[((size_t)(b * 256 + row)) * 512 + h * 64 + f * 16 + c] = f2bf(val);
    }
}

// ---------------------------------------------------------------------------
extern "C" void kernel_launch(void* const* d_in, const int* in_sizes, int n_in,
                              void* d_out, int out_size, void* d_ws, size_t ws_size,
                              hipStream_t stream) {
  const float* x       = (const float*)d_in[0];
  const float* pos     = (const float*)d_in[1];
  const float* W_pos   = (const float*)d_in[2];
  const float* b_pos   = (const float*)d_in[3];
  const float* W_in    = (const float*)d_in[4];
  const float* b_in    = (const float*)d_in[5];
  const float* latents = (const float*)d_in[6];
  const float* lnq_g   = (const float*)d_in[7];
  const float* lnq_b   = (const float*)d_in[8];
  const float* lnk_g   = (const float*)d_in[9];
  const float* lnk_b   = (const float*)d_in[10];
  const float* lnv_g   = (const float*)d_in[11];
  const float* lnv_b   = (const float*)d_in[12];
  const float* cWq     = (const float*)d_in[13];
  const float* cWk     = (const float*)d_in[14];
  const float* cWv     = (const float*)d_in[15];
  const float* cWo     = (const float*)d_in[16];
  const float* c_bo    = (const float*)d_in[17];
  const float* ln1_g   = (const float*)d_in[18];
  const float* ln1_b   = (const float*)d_in[19];
  const float* sWq     = (const float*)d_in[20];
  const float* sWkv    = (const float*)d_in[21];
  const float* sWo     = (const float*)d_in[22];
  const float* s_bo    = (const float*)d_in[23];
  const float* ln2_g   = (const float*)d_in[24];
  const float* ln2_b   = (const float*)d_in[25];
  const float* fW1     = (const float*)d_in[26];
  const float* f_b1    = (const float*)d_in[27];
  const float* fW2     = (const float*)d_in[28];
  const float* f_b2    = (const float*)d_in[29];
  const float* lnf_g   = (const float*)d_in[30];
  const float* lnf_b   = (const float*)d_in[31];
  const float* Wb      = (const float*)d_in[32];
  const float* bbv     = (const float*)d_in[33];
  float* outp = (float*)d_out;

  // bf16 transposed weight offsets (elements)
  size_t W = 0;
  size_t o_cWq = W; W += 512 * 512;
  size_t o_cWk = W; W += 512 * 512;
  size_t o_cWv = W; W += 512 * 512;
  size_t o_cWo = W; W += 512 * 512;
  size_t o_Wb  = W; W += 64 * 512;
  size_t o_Wpos = W; W += 512 * 64;
  size_t o_sQKV[6], o_sWo[6], o_fW1[6], o_fW2[6];
  for (int i = 0; i < 6; ++i) {
    o_sQKV[i] = W; W += 1536 * 512;   // q rows 0..511, kv rows 512..1535
    o_sWo[i]  = W; W += 512 * 512;
    o_fW1[i]  = W; W += 2048 * 512;
    o_fW2[i]  = W; W += 512 * 2048;
  }
  MatTable T;
  int nm = 0;
  auto add = [&](const float* s, int K, int N, int kp, size_t off) {
    T.m[nm].src = s; T.m[nm].K = K; T.m[nm].N = N; T.m[nm].kp = kp;
    T.m[nm].off = (int)off; ++nm;
  };
  add(cWq, 512, 512, 512, o_cWq); add(cWk, 512, 512, 512, o_cWk);
  add(cWv, 512, 512, 512, o_cWv); add(cWo, 512, 512, 512, o_cWo);
  add(Wb, 512, 64, 512, o_Wb);
  add(W_pos, 48, 512, 64, o_Wpos);
  for (int i = 0; i < 6; ++i) {
    add(sWq  + (size_t)i * 512 * 512,  512, 512,  512, o_sQKV[i]);
    add(sWkv + (size_t)i * 512 * 1024, 512, 1024, 512, o_sQKV[i] + 512 * 512);
    add(sWo  + (size_t)i * 512 * 512,  512, 512,  512, o_sWo[i]);
    add(fW1  + (size_t)i * 512 * 2048, 512, 2048, 512, o_fW1[i]);
    add(fW2  + (size_t)i * 2048 * 512, 2048, 512, 2048, o_fW2[i]);
  }

  // workspace carve
  char* p = (char*)d_ws;
  auto carve = [&](size_t bytes) {
    char* r = p; p += (bytes + 255) & ~(size_t)255; return r;
  };
  short* wtb   = (short*)carve(W * 2);
  short* enc   = (short*)carve((size_t)32768 * 64 * 2);   // 4MB
  short* kn    = (short*)carve(33554432);                 // 32MB
  short* vn    = (short*)carve(33554432);                 // 32MB
  short* kvc   = (short*)carve((size_t)32768 * 1024 * 2); // 64MB
  short* latn0 = (short*)carve(262144);
  short* qc    = (short*)carve(262144);
  float* lat   = (float*)carve(4194304);
  // aliases into dead regions
  short* attno = kn;                               // kn dead after kproj GEMM
  short* h     = vn;                               // vn dead after vproj GEMM
  short* qkv   = (short*)((char*)vn + 2097152);    // [2048,1536] bf16 = 6MB
  short* ffh   = (short*)((char*)vn + 8388608);    // [2048,2048] bf16 = 8MB

  wtrans_kernel<<<dim3(1024, 36), 256, 0, stream>>>(T, wtb);
  enc_kernel<<<1024, 256, 0, stream>>>(pos, enc);
  embed2_kernel<<<256, 512, 0, stream>>>(enc, wtb + o_Wpos, b_pos, W_in, b_in, x,
                                         lnk_g, lnk_b, lnv_g, lnv_b, kn, vn);
  bcast_kernel<<<4096, 256, 0, stream>>>(latents, lat);
  ln_kernel<<<64, 256, 0, stream>>>(latents, lnq_g, lnq_b, latn0, 256);
  gemm64_kernel<0><<<dim3(8, 4), 256, 0, stream>>>(latn0, wtb + o_cWq, nullptr, qc, 256, 512, 512, 512);
  gemm_kernel<0><<<dim3(4, 256), 256, 0, stream>>>(kn, wtb + o_cWk, nullptr, kvc, 32768, 512, 512, 1024);
  gemm_kernel<0><<<dim3(4, 256), 256, 0, stream>>>(vn, wtb + o_cWv, nullptr, kvc + 512, 32768, 512, 512, 1024);
  flash_kernel<<<dim3(4, 8, 8), 256, 0, stream>>>(qc, kvc, kvc + 512, attno,
                                                  512, 0, (long)4096 * 1024, 1024, 4096);
  gemm64_kernel<2><<<dim3(8, 32), 256, 0, stream>>>(attno, wtb + o_cWo, c_bo, lat, 2048, 512, 512, 512);

  for (int i = 0; i < 6; ++i) {
    ln_kernel<<<512, 256, 0, stream>>>(lat, ln1_g + i * 512, ln1_b + i * 512, h, 2048);
    gemm64_kernel<0><<<dim3(24, 32), 256, 0, stream>>>(h, wtb + o_sQKV[i], nullptr, qkv, 2048, 1536, 512, 1536);
    flash_kernel<<<dim3(4, 8, 8), 256, 0, stream>>>(qkv, qkv + 512, qkv + 1024, attno,
                                                    1536, 256, (long)256 * 1536, 1536, 256);
    gemm64_kernel<2><<<dim3(8, 32), 256, 0, stream>>>(attno, wtb + o_sWo[i], s_bo + i * 512, lat, 2048, 512, 512, 512);
    ln_kernel<<<512, 256, 0, stream>>>(lat, ln2_g + i * 512, ln2_b + i * 512, h, 2048);
    gemm_kernel<1><<<dim3(16, 16), 256, 0, stream>>>(h, wtb + o_fW1[i], f_b1 + i * 2048, ffh, 2048, 2048, 512, 2048);
    gemm64_kernel<2><<<dim3(8, 32), 256, 0, stream>>>(ffh, wtb + o_fW2[i], f_b2 + i * 512, lat, 2048, 512, 2048, 512);
  }
  ln_kernel<<<512, 256, 0, stream>>>(lat, lnf_g, lnf_b, h, 2048);
  gemm64_kernel<3><<<dim3(1, 32), 256, 0, stream>>>(h, wtb + o_Wb, bbv, outp, 2048, 64, 512, 64);
}

// Round 3
// 798.925 us; speedup vs baseline: 2.1936x; 1.1124x over previous
//
#include <hip/hip_runtime.h>
#include <hip/hip_bf16.h>

#define DEV __device__ __forceinline__

typedef __attribute__((ext_vector_type(8))) short short8;
typedef __attribute__((ext_vector_type(4))) float floatx4;

DEV short f2bf(float f) {
  unsigned u = __float_as_uint(f);
  u += 0x7fffu + ((u >> 16) & 1u);
  return (short)(u >> 16);
}
DEV float bf2f(short s) {
  return __uint_as_float(((unsigned)(unsigned short)s) << 16);
}
DEV float wred(float v) {
#pragma unroll
  for (int m = 1; m < 64; m <<= 1) v += __shfl_xor(v, m);
  return v;
}
DEV floatx4 mfma16(short8 a, short8 b, floatx4 c) {
  return __builtin_amdgcn_mfma_f32_16x16x32_bf16(a, b, c, 0, 0, 0);
}
// async global->LDS, 16B per lane, dest = wave-uniform base + lane*16
DEV void gload16(void* lds, const void* g) {
  __builtin_amdgcn_global_load_lds(
      (const __attribute__((address_space(1))) unsigned int*)g,
      (__attribute__((address_space(3))) unsigned int*)lds, 16, 0, 0);
}

// ---------------------------------------------------------------------------
// Weight transpose+convert: src fp32 [K,N] -> dst bf16 [N][kp] (zero pad K..kp)
// ---------------------------------------------------------------------------
struct MatDesc { const float* src; int K; int N; int kp; int off; };
struct MatTable { MatDesc m[36]; };

__global__ __launch_bounds__(256) void wtrans_kernel(MatTable T, short* __restrict__ dst) {
  int mi = blockIdx.y;
  MatDesc d = T.m[mi];
  int tilesx = d.N >> 5, tilesy = d.kp >> 5;
  int tb = blockIdx.x;
  if (tb >= tilesx * tilesy) return;
  int ty = tb / tilesx, tx = tb % tilesx;
  __shared__ float tile[32][33];
  int tid = threadIdx.x;
#pragma unroll
  for (int i = 0; i < 4; ++i) {
    int e = tid + i * 256, lr = e >> 5, lc = e & 31;
    int kk = ty * 32 + lr;
    tile[lr][lc] = (kk < d.K) ? d.src[(size_t)kk * d.N + tx * 32 + lc] : 0.f;
  }
  __syncthreads();
#pragma unroll
  for (int i = 0; i < 4; ++i) {
    int e = tid + i * 256, lr = e >> 5, lc = e & 31;
    dst[(size_t)d.off + (size_t)(tx * 32 + lr) * d.kp + ty * 32 + lc] = f2bf(tile[lc][lr]);
  }
}

// ---------------------------------------------------------------------------
// NeRF encode -> enc bf16 [32768, 64] (k 48..63 = 0)
// ---------------------------------------------------------------------------
__global__ __launch_bounds__(256) void enc_kernel(const float* __restrict__ pos,
                                                  short* __restrict__ enc) {
  int idx = blockIdx.x * 256 + threadIdx.x;
  int row = idx >> 3, oct = idx & 7;
  float p0 = pos[row * 2], p1 = pos[row * 2 + 1];
  short8 o;
#pragma unroll
  for (int j = 0; j < 8; ++j) {
    int k = oct * 8 + j;
    float val = 0.f;
    if (k < 48) {
      int dd = k / 24, rem = k % 24;
      int trig = rem / 12, f = rem % 12;
      float ang = (dd ? p1 : p0) * exp2f((4.0f / 11.0f) * (float)f);
      val = trig ? __cosf(ang) : __sinf(ang);
    }
    o[j] = f2bf(val);
  }
  *(short8*)&enc[(size_t)row * 64 + oct * 8] = o;
}

// ---------------------------------------------------------------------------
// Fused pos-embed GEMM (enc @ W_pos^T, K=64) + relu + x@W_in + LN(k), LN(v)
// 512 threads = 8 waves; block = 128 rows; wave = 16 rows x 512 cols.
// Output: knvn [32768][1024], LN(k) in cols 0..511, LN(v) in cols 512..1023.
// ---------------------------------------------------------------------------
__global__ __launch_bounds__(512) void embed2_kernel(
    const short* __restrict__ enc, const short* __restrict__ Wt,  // [512][64]
    const float* __restrict__ b_pos, const float* __restrict__ W_in,
    const float* __restrict__ b_in, const float* __restrict__ x,
    const float* __restrict__ lnk_g, const float* __restrict__ lnk_b,
    const float* __restrict__ lnv_g, const float* __restrict__ lnv_b,
    short* __restrict__ knvn) {
  __shared__ short Wl[512 * 64];
  __shared__ short El[128 * 64];
  int tid = threadIdx.x;
  int lane = tid & 63, wv = tid >> 6;
  int c = lane & 15, g = lane >> 4;
  int blk = blockIdx.x * 128;
#pragma unroll
  for (int gi = 0; gi < 8; ++gi) {
    int grp = wv * 8 + gi;
    int row = grp * 8 + (lane >> 3), kc = lane & 7;
    gload16(&Wl[grp * 512], &Wt[(size_t)row * 64 + ((kc ^ (row & 7)) * 8)]);
  }
#pragma unroll
  for (int gi = 0; gi < 2; ++gi) {
    int grp = wv * 2 + gi;
    int row = grp * 8 + (lane >> 3), kc = lane & 7;
    gload16(&El[grp * 512], &enc[(size_t)(blk + row) * 64 + ((kc ^ (row & 7)) * 8)]);
  }
  __syncthreads();

  floatx4 acc[32];
  floatx4 zf = {0.f, 0.f, 0.f, 0.f};
#pragma unroll
  for (int nf = 0; nf < 32; ++nf) acc[nf] = zf;
  short8 af[2];
#pragma unroll
  for (int ks = 0; ks < 2; ++ks)
    af[ks] = *(const short8*)&El[(wv * 16 + c) * 64 + ((ks * 4 + g) ^ (c & 7)) * 8];
#pragma unroll
  for (int nf = 0; nf < 32; ++nf) {
#pragma unroll
    for (int ks = 0; ks < 2; ++ks) {
      short8 bf8 = *(const short8*)&Wl[(nf * 16 + c) * 64 + ((ks * 4 + g) ^ (c & 7)) * 8];
      acc[nf] = mfma16(af[ks], bf8, acc[nf]);
    }
  }

  int rowbase = blk + wv * 16 + g * 4;
  float x0[4], x1[4], x2[4];
  float s1[4], q1[4], s2[4], q2[4];
#pragma unroll
  for (int r = 0; r < 4; ++r) {
    x0[r] = x[(size_t)(rowbase + r) * 3];
    x1[r] = x[(size_t)(rowbase + r) * 3 + 1];
    x2[r] = x[(size_t)(rowbase + r) * 3 + 2];
    s1[r] = 0; q1[r] = 0; s2[r] = 0; q2[r] = 0;
  }
#pragma unroll
  for (int nf = 0; nf < 32; ++nf) {
    int col = nf * 16 + c;
    float bp = b_pos[col];
    float w0 = W_in[col], w1 = W_in[512 + col], w2 = W_in[1024 + col], bi = b_in[col];
#pragma unroll
    for (int r = 0; r < 4; ++r) {
      float kk = fmaxf(acc[nf][r] + bp, 0.f);
      float vv = kk + x0[r] * w0 + x1[r] * w1 + x2[r] * w2 + bi;
      acc[nf][r] = kk;
      s1[r] += kk; q1[r] += kk * kk; s2[r] += vv; q2[r] += vv * vv;
    }
  }
  float m1[4], r1[4], m2[4], r2[4];
#pragma unroll
  for (int r = 0; r < 4; ++r) {
#pragma unroll
    for (int msk = 1; msk < 16; msk <<= 1) {
      s1[r] += __shfl_xor(s1[r], msk); q1[r] += __shfl_xor(q1[r], msk);
      s2[r] += __shfl_xor(s2[r], msk); q2[r] += __shfl_xor(q2[r], msk);
    }
    m1[r] = s1[r] * (1.f / 512.f);
    r1[r] = rsqrtf(q1[r] * (1.f / 512.f) - m1[r] * m1[r] + 1e-5f);
    m2[r] = s2[r] * (1.f / 512.f);
    r2[r] = rsqrtf(q2[r] * (1.f / 512.f) - m2[r] * m2[r] + 1e-5f);
  }
#pragma unroll
  for (int nf = 0; nf < 32; ++nf) {
    int col = nf * 16 + c;
    float w0 = W_in[col], w1 = W_in[512 + col], w2 = W_in[1024 + col], bi = b_in[col];
    float gk = lnk_g[col], bk = lnk_b[col], gv = lnv_g[col], bv = lnv_b[col];
#pragma unroll
    for (int r = 0; r < 4; ++r) {
      float kk = acc[nf][r];
      float vv = kk + x0[r] * w0 + x1[r] * w1 + x2[r] * w2 + bi;
      size_t ridx = (size_t)(rowbase + r) * 1024;
      knvn[ridx + col] = f2bf((kk - m1[r]) * r1[r] * gk + bk);
      knvn[ridx + 512 + col] = f2bf((vv - m2[r]) * r2[r] * gv + bv);
    }
  }
}

// ---------------------------------------------------------------------------
// LayerNorm fp32 in [M,512] -> bf16 out, one wave per row
// ---------------------------------------------------------------------------
__global__ __launch_bounds__(256) void ln_kernel(
    const float* __restrict__ in, const float* __restrict__ g,
    const float* __restrict__ b, short* __restrict__ out, int M) {
  int row = blockIdx.x * 4 + (threadIdx.x >> 6);
  if (row >= M) return;
  int lane = threadIdx.x & 63;
  float v[8]; float s = 0, q = 0;
#pragma unroll
  for (int j = 0; j < 8; ++j) {
    v[j] = in[(size_t)row * 512 + lane + 64 * j];
    s += v[j]; q += v[j] * v[j];
  }
  s = wred(s); q = wred(q);
  float m = s * (1.f / 512.f);
  float rs = rsqrtf(q * (1.f / 512.f) - m * m + 1e-5f);
#pragma unroll
  for (int j = 0; j < 8; ++j) {
    int cc = lane + 64 * j;
    out[(size_t)row * 512 + cc] = f2bf((v[j] - m) * rs * g[cc] + b[cc]);
  }
}

// broadcast latents [256,512] -> lat [2048,512] fp32
__global__ void bcast_kernel(const float* __restrict__ latents, float* __restrict__ lat) {
  int i = blockIdx.x * 256 + threadIdx.x;
  lat[i] = latents[i & 131071];
}

// ---------------------------------------------------------------------------
// Shared GEMM epilogue op
// EPI: 0 = bf16 out, 1 = gelu->bf16, 2 = fp32 residual +=, 3 = fp32 out
// ---------------------------------------------------------------------------
template <int EPI>
DEV void epi_store(void* outp, size_t idx, float xv) {
  if (EPI == 0) {
    ((short*)outp)[idx] = f2bf(xv);
  } else if (EPI == 1) {
    float t = 0.7978845608f * (xv + 0.044715f * xv * xv * xv);
    ((short*)outp)[idx] = f2bf(0.5f * xv * (1.f + tanhf(t)));
  } else if (EPI == 2) {
    ((float*)outp)[idx] += xv;
  } else {
    ((float*)outp)[idx] = xv;
  }
}

// ---------------------------------------------------------------------------
// GEMM 128x128 tile, BK=64, 4 waves (2x2). A bf16 [M,*lda]; Wt bf16 [N][K].
// ---------------------------------------------------------------------------
template <int EPI>
__global__ __launch_bounds__(256) void gemm_kernel(
    const short* __restrict__ A, const short* __restrict__ Wt,
    const float* __restrict__ bias, void* __restrict__ outp,
    int M, int N, int K, int lda, int ldo) {
  __shared__ short Alds[128 * 64];
  __shared__ short Blds[128 * 64];
  int tid = threadIdx.x;
  int brow = blockIdx.y * 128, bcol = blockIdx.x * 128;
  int lane = tid & 63, wvid = tid >> 6;
  int wr = wvid >> 1, wc = wvid & 1;
  int g = lane >> 4, c = lane & 15;
  floatx4 zf = {0.f, 0.f, 0.f, 0.f};
  floatx4 acc[4][4];
#pragma unroll
  for (int i = 0; i < 4; ++i)
#pragma unroll
    for (int j = 0; j < 4; ++j) acc[i][j] = zf;

  int srow = (lane >> 3), skc = lane & 7;
  for (int k0 = 0; k0 < K; k0 += 64) {
#pragma unroll
    for (int gi = 0; gi < 4; ++gi) {
      int grp = wvid * 4 + gi;
      int row = grp * 8 + srow;
      int sw = ((skc ^ (row & 7)) * 8);
      gload16(&Alds[grp * 512], &A[(size_t)(brow + row) * lda + k0 + sw]);
      gload16(&Blds[grp * 512], &Wt[(size_t)(bcol + row) * K + k0 + sw]);
    }
    __syncthreads();
#pragma unroll
    for (int ks = 0; ks < 2; ++ks) {
      int slot = ((ks * 4 + g) ^ (c & 7)) * 8;
      short8 af[4], bf8[4];
#pragma unroll
      for (int mf = 0; mf < 4; ++mf)
        af[mf] = *(const short8*)&Alds[(wr * 64 + mf * 16 + c) * 64 + slot];
#pragma unroll
      for (int nf = 0; nf < 4; ++nf)
        bf8[nf] = *(const short8*)&Blds[(wc * 64 + nf * 16 + c) * 64 + slot];
#pragma unroll
      for (int mf = 0; mf < 4; ++mf)
#pragma unroll
        for (int nf = 0; nf < 4; ++nf)
          acc[mf][nf] = mfma16(af[mf], bf8[nf], acc[mf][nf]);
    }
    __syncthreads();
  }

#pragma unroll
  for (int mf = 0; mf < 4; ++mf) {
#pragma unroll
    for (int nf = 0; nf < 4; ++nf) {
      int col = bcol + wc * 64 + nf * 16 + c;
      float bv = bias ? bias[col] : 0.f;
      int row0 = brow + wr * 64 + mf * 16 + g * 4;
#pragma unroll
      for (int r = 0; r < 4; ++r)
        epi_store<EPI>(outp, (size_t)(row0 + r) * ldo + col, acc[mf][nf][r] + bv);
    }
  }
}

// ---------------------------------------------------------------------------
// GEMM 64x64 tile. 4 waves (2x2), each wave 32x32.
// ---------------------------------------------------------------------------
template <int EPI>
__global__ __launch_bounds__(256) void gemm64_kernel(
    const short* __restrict__ A, const short* __restrict__ Wt,
    const float* __restrict__ bias, void* __restrict__ outp,
    int M, int N, int K, int lda, int ldo) {
  __shared__ short Alds[64 * 64];
  __shared__ short Blds[64 * 64];
  int tid = threadIdx.x;
  int brow = blockIdx.y * 64, bcol = blockIdx.x * 64;
  int lane = tid & 63, wvid = tid >> 6;
  int wr = wvid >> 1, wc = wvid & 1;
  int g = lane >> 4, c = lane & 15;
  floatx4 zf = {0.f, 0.f, 0.f, 0.f};
  floatx4 acc[2][2];
#pragma unroll
  for (int i = 0; i < 2; ++i)
#pragma unroll
    for (int j = 0; j < 2; ++j) acc[i][j] = zf;

  int srow = (lane >> 3), skc = lane & 7;
  for (int k0 = 0; k0 < K; k0 += 64) {
#pragma unroll
    for (int gi = 0; gi < 2; ++gi) {
      int grp = wvid * 2 + gi;
      int row = grp * 8 + srow;
      int sw = ((skc ^ (row & 7)) * 8);
      gload16(&Alds[grp * 512], &A[(size_t)(brow + row) * lda + k0 + sw]);
      gload16(&Blds[grp * 512], &Wt[(size_t)(bcol + row) * K + k0 + sw]);
    }
    __syncthreads();
#pragma unroll
    for (int ks = 0; ks < 2; ++ks) {
      int slot = ((ks * 4 + g) ^ (c & 7)) * 8;
      short8 af[2], bf8[2];
#pragma unroll
      for (int mf = 0; mf < 2; ++mf)
        af[mf] = *(const short8*)&Alds[(wr * 32 + mf * 16 + c) * 64 + slot];
#pragma unroll
      for (int nf = 0; nf < 2; ++nf)
        bf8[nf] = *(const short8*)&Blds[(wc * 32 + nf * 16 + c) * 64 + slot];
#pragma unroll
      for (int mf = 0; mf < 2; ++mf)
#pragma unroll
        for (int nf = 0; nf < 2; ++nf)
          acc[mf][nf] = mfma16(af[mf], bf8[nf], acc[mf][nf]);
    }
    __syncthreads();
  }

#pragma unroll
  for (int mf = 0; mf < 2; ++mf) {
#pragma unroll
    for (int nf = 0; nf < 2; ++nf) {
      int col = bcol + wc * 32 + nf * 16 + c;
      float bv = bias ? bias[col] : 0.f;
      int row0 = brow + wr * 32 + mf * 16 + g * 4;
#pragma unroll
      for (int r = 0; r < 4; ++r)
        epi_store<EPI>(outp, (size_t)(row0 + r) * ldo + col, acc[mf][nf][r] + bv);
    }
  }
}

// ---------------------------------------------------------------------------
// Split-KV flash attention. Block = (qt, h, b*nseg+seg). Each block processes
// seglen KV tokens, writes unnormalized partial O (fp32) + running m, l.
// Partial layouts: po[(seg*2048 + b*256 + row)*512 + h*64 + d] fp32
//                  pm/pl[(seg*2048 + b*256 + row)*8 + h] fp32
// ---------------------------------------------------------------------------
__global__ __launch_bounds__(256) void flashsp_kernel(
    const short* __restrict__ q, const short* __restrict__ k,
    const short* __restrict__ v, float* __restrict__ po,
    float* __restrict__ pm, float* __restrict__ pl,
    int qrs, int qbrows, long kvbstride, int kvrstride,
    int seglen, int lognseg) {
  __shared__ short Qs[64 * 64];
  __shared__ short Ks[64 * 64];
  __shared__ short Vt[64 * 72];
  __shared__ short Ps[64 * 72];
  int tid = threadIdx.x;
  int bz = blockIdx.z;
  int b = bz >> lognseg, seg = bz & ((1 << lognseg) - 1);
  int h = blockIdx.y, qt = blockIdx.x;
  int lane = tid & 63, wv = tid >> 6;
  int g = lane >> 4, c = lane & 15;
  int srow = lane >> 3, skc = lane & 7;

#pragma unroll
  for (int gi = 0; gi < 2; ++gi) {
    int grp = wv * 2 + gi;
    int row = grp * 8 + srow;
    int sw = ((skc ^ (row & 7)) * 8);
    gload16(&Qs[grp * 512],
            &q[((size_t)(b * qbrows) + qt * 64 + row) * qrs + h * 64 + sw]);
  }

  float m_[4], l_[4];
  floatx4 zf = {0.f, 0.f, 0.f, 0.f};
  floatx4 o_[4];
#pragma unroll
  for (int r = 0; r < 4; ++r) { m_[r] = -3.0e38f; l_[r] = 0.f; }
#pragma unroll
  for (int f = 0; f < 4; ++f) o_[f] = zf;

  int tbeg = seg * seglen, tend = tbeg + seglen;
  for (int t0 = tbeg; t0 < tend; t0 += 64) {
#pragma unroll
    for (int gi = 0; gi < 2; ++gi) {
      int grp = wv * 2 + gi;
      int row = grp * 8 + srow;
      int sw = ((skc ^ (row & 7)) * 8);
      gload16(&Ks[grp * 512],
              &k[(size_t)b * kvbstride + (size_t)(t0 + row) * kvrstride + h * 64 + sw]);
    }
#pragma unroll
    for (int it = 0; it < 2; ++it) {
      int ch = tid + it * 256;
      int j = ch >> 3, f0 = (ch & 7) * 8, mm = ch & 7, tg = j >> 3;
      short8 tv = *(const short8*)&v[(size_t)b * kvbstride + (size_t)(t0 + j) * kvrstride + h * 64 + f0];
#pragma unroll
      for (int jj = 0; jj < 8; ++jj)
        Vt[(f0 + jj) * 72 + ((tg ^ mm) * 8) + (j & 7)] = tv[jj];
    }
    __syncthreads();

    floatx4 s[4];
#pragma unroll
    for (int f = 0; f < 4; ++f) s[f] = zf;
#pragma unroll
    for (int ks = 0; ks < 2; ++ks) {
      int slot = ((ks * 4 + g) ^ (c & 7)) * 8;
      short8 a = *(const short8*)&Qs[(wv * 16 + c) * 64 + slot];
#pragma unroll
      for (int f = 0; f < 4; ++f) {
        short8 b8 = *(const short8*)&Ks[(f * 16 + c) * 64 + slot];
        s[f] = mfma16(a, b8, s[f]);
      }
    }
#pragma unroll
    for (int f = 0; f < 4; ++f)
#pragma unroll
      for (int r = 0; r < 4; ++r) s[f][r] *= 0.125f;

    float nm[4], sf[4], rs[4];
#pragma unroll
    for (int r = 0; r < 4; ++r) {
      float t = fmaxf(fmaxf(s[0][r], s[1][r]), fmaxf(s[2][r], s[3][r]));
#pragma unroll
      for (int msk = 1; msk < 16; msk <<= 1) t = fmaxf(t, __shfl_xor(t, msk));
      nm[r] = fmaxf(m_[r], t);
      sf[r] = __expf(m_[r] - nm[r]);
      rs[r] = 0.f;
    }
#pragma unroll
    for (int f = 0; f < 4; ++f)
#pragma unroll
      for (int r = 0; r < 4; ++r) {
        float p = __expf(s[f][r] - nm[r]);
        s[f][r] = p; rs[r] += p;
      }
#pragma unroll
    for (int r = 0; r < 4; ++r) {
#pragma unroll
      for (int msk = 1; msk < 16; msk <<= 1) rs[r] += __shfl_xor(rs[r], msk);
      l_[r] = l_[r] * sf[r] + rs[r];
      m_[r] = nm[r];
    }
#pragma unroll
    for (int f = 0; f < 4; ++f)
#pragma unroll
      for (int r = 0; r < 4; ++r) o_[f][r] *= sf[r];
#pragma unroll
    for (int f = 0; f < 4; ++f)
#pragma unroll
      for (int r = 0; r < 4; ++r)
        Ps[(wv * 16 + g * 4 + r) * 72 + f * 16 + c] = f2bf(s[f][r]);
    __syncthreads();
#pragma unroll
    for (int ks = 0; ks < 2; ++ks) {
      short8 pa = *(const short8*)&Ps[(wv * 16 + c) * 72 + ks * 32 + g * 8];
#pragma unroll
      for (int f = 0; f < 4; ++f) {
        int mm = (2 * f + (c >> 3)) & 7;
        short8 vb = *(const short8*)&Vt[(f * 16 + c) * 72 + ((ks * 4 + g) ^ mm) * 8];
        o_[f] = mfma16(pa, vb, o_[f]);
      }
    }
    __syncthreads();
  }

#pragma unroll
  for (int f = 0; f < 4; ++f)
#pragma unroll
    for (int r = 0; r < 4; ++r) {
      int row = qt * 64 + wv * 16 + g * 4 + r;
      size_t grow = (size_t)seg * 2048 + b * 256 + row;
      po[grow * 512 + h * 64 + f * 16 + c] = o_[f][r];
      if (f == 0 && c == 0) {
        pm[grow * 8 + h] = m_[r];
        pl[grow * 8 + h] = l_[r];
      }
    }
}

// ---------------------------------------------------------------------------
// Combine NSEG partial attention results -> bf16 out [2048,512]
// ---------------------------------------------------------------------------
template <int NSEG>
__global__ __launch_bounds__(256) void fcomb_kernel(
    const float* __restrict__ po, const float* __restrict__ pm,
    const float* __restrict__ pl, short* __restrict__ out) {
  int idx = blockIdx.x * 256 + threadIdx.x;  // over 2048*512
  int grow = idx >> 9, col = idx & 511, h = col >> 6;
  float ms[NSEG];
  float M = -3.0e38f;
#pragma unroll
  for (int s = 0; s < NSEG; ++s) {
    ms[s] = pm[((size_t)s * 2048 + grow) * 8 + h];
    M = fmaxf(M, ms[s]);
  }
  float L = 0.f, acc = 0.f;
#pragma unroll
  for (int s = 0; s < NSEG; ++s) {
    float w = __expf(ms[s] - M);
    L += w * pl[((size_t)s * 2048 + grow) * 8 + h];
    acc += w * po[((size_t)s * 2048 + grow) * 512 + col];
  }
  out[idx] = f2bf(acc / L);
}

// ---------------------------------------------------------------------------
extern "C" void kernel_launch(void* const* d_in, const int* in_sizes, int n_in,
                              void* d_out, int out_size, void* d_ws, size_t ws_size,
                              hipStream_t stream) {
  const float* x       = (const float*)d_in[0];
  const float* pos     = (const float*)d_in[1];
  const float* W_pos   = (const float*)d_in[2];
  const float* b_pos   = (const float*)d_in[3];
  const float* W_in    = (const float*)d_in[4];
  const float* b_in    = (const float*)d_in[5];
  const float* latents = (const float*)d_in[6];
  const float* lnq_g   = (const float*)d_in[7];
  const float* lnq_b   = (const float*)d_in[8];
  const float* lnk_g   = (const float*)d_in[9];
  const float* lnk_b   = (const float*)d_in[10];
  const float* lnv_g   = (const float*)d_in[11];
  const float* lnv_b   = (const float*)d_in[12];
  const float* cWq     = (const float*)d_in[13];
  const float* cWk     = (const float*)d_in[14];
  const float* cWv     = (const float*)d_in[15];
  const float* cWo     = (const float*)d_in[16];
  const float* c_bo    = (const float*)d_in[17];
  const float* ln1_g   = (const float*)d_in[18];
  const float* ln1_b   = (const float*)d_in[19];
  const float* sWq     = (const float*)d_in[20];
  const float* sWkv    = (const float*)d_in[21];
  const float* sWo     = (const float*)d_in[22];
  const float* s_bo    = (const float*)d_in[23];
  const float* ln2_g   = (const float*)d_in[24];
  const float* ln2_b   = (const float*)d_in[25];
  const float* fW1     = (const float*)d_in[26];
  const float* f_b1    = (const float*)d_in[27];
  const float* fW2     = (const float*)d_in[28];
  const float* f_b2    = (const float*)d_in[29];
  const float* lnf_g   = (const float*)d_in[30];
  const float* lnf_b   = (const float*)d_in[31];
  const float* Wb      = (const float*)d_in[32];
  const float* bbv     = (const float*)d_in[33];
  float* outp = (float*)d_out;

  // bf16 transposed weight offsets (elements)
  size_t W = 0;
  size_t o_cWq = W; W += 512 * 512;
  size_t o_cWk = W; W += 512 * 512;
  size_t o_cWv = W; W += 512 * 512;
  size_t o_cWo = W; W += 512 * 512;
  size_t o_Wb  = W; W += 64 * 512;
  size_t o_Wpos = W; W += 512 * 64;
  size_t o_sQKV[6], o_sWo[6], o_fW1[6], o_fW2[6];
  for (int i = 0; i < 6; ++i) {
    o_sQKV[i] = W; W += 1536 * 512;   // q rows 0..511, kv rows 512..1535
    o_sWo[i]  = W; W += 512 * 512;
    o_fW1[i]  = W; W += 2048 * 512;
    o_fW2[i]  = W; W += 512 * 2048;
  }
  MatTable T;
  int nm = 0;
  auto add = [&](const float* s, int K, int N, int kp, size_t off) {
    T.m[nm].src = s; T.m[nm].K = K; T.m[nm].N = N; T.m[nm].kp = kp;
    T.m[nm].off = (int)off; ++nm;
  };
  add(cWq, 512, 512, 512, o_cWq); add(cWk, 512, 512, 512, o_cWk);
  add(cWv, 512, 512, 512, o_cWv); add(cWo, 512, 512, 512, o_cWo);
  add(Wb, 512, 64, 512, o_Wb);
  add(W_pos, 48, 512, 64, o_Wpos);
  for (int i = 0; i < 6; ++i) {
    add(sWq  + (size_t)i * 512 * 512,  512, 512,  512, o_sQKV[i]);
    add(sWkv + (size_t)i * 512 * 1024, 512, 1024, 512, o_sQKV[i] + 512 * 512);
    add(sWo  + (size_t)i * 512 * 512,  512, 512,  512, o_sWo[i]);
    add(fW1  + (size_t)i * 512 * 2048, 512, 2048, 512, o_fW1[i]);
    add(fW2  + (size_t)i * 2048 * 512, 2048, 512, 2048, o_fW2[i]);
  }

  // workspace carve
  char* p = (char*)d_ws;
  auto carve = [&](size_t bytes) {
    char* r = p; p += (bytes + 255) & ~(size_t)255; return r;
  };
  short* wtb   = (short*)carve(W * 2);                     // ~40MB
  short* enc   = (short*)carve((size_t)32768 * 64 * 2);    // 4MB
  short* knvn  = (short*)carve((size_t)32768 * 1024 * 2);  // 64MB  [k | v]
  short* kvc   = (short*)carve((size_t)32768 * 1024 * 2);  // 64MB  [K | V]
  short* latn0 = (short*)carve(262144);
  short* qc    = (short*)carve(262144);
  float* lat   = (float*)carve(4194304);
  float* pm    = (float*)carve(1048576);                   // 8 segs max
  float* pl    = (float*)carve(1048576);
  // aliases into dead regions:
  short* attno = enc;                                  // enc dead after embed2
  float* po    = (float*)knvn;                         // knvn dead after projections; 34MB max
  short* h     = (short*)((char*)knvn + 36 * 1048576); // 2MB
  short* qkv   = (short*)((char*)knvn + 40 * 1048576); // 6MB
  short* ffh   = (short*)((char*)knvn + 48 * 1048576); // 8MB

  wtrans_kernel<<<dim3(1024, 36), 256, 0, stream>>>(T, wtb);
  enc_kernel<<<1024, 256, 0, stream>>>(pos, enc);
  embed2_kernel<<<256, 512, 0, stream>>>(enc, wtb + o_Wpos, b_pos, W_in, b_in, x,
                                         lnk_g, lnk_b, lnv_g, lnv_b, knvn);
  bcast_kernel<<<4096, 256, 0, stream>>>(latents, lat);
  ln_kernel<<<64, 256, 0, stream>>>(latents, lnq_g, lnq_b, latn0, 256);
  gemm64_kernel<0><<<dim3(8, 4), 256, 0, stream>>>(latn0, wtb + o_cWq, nullptr, qc, 256, 512, 512, 512, 512);
  gemm_kernel<0><<<dim3(4, 256), 256, 0, stream>>>(knvn, wtb + o_cWk, nullptr, kvc, 32768, 512, 512, 1024, 1024);
  gemm_kernel<0><<<dim3(4, 256), 256, 0, stream>>>(knvn + 512, wtb + o_cWv, nullptr, kvc + 512, 32768, 512, 512, 1024, 1024);
  // cross attention: 8 KV segments of 512 tokens
  flashsp_kernel<<<dim3(4, 8, 64), 256, 0, stream>>>(qc, kvc, kvc + 512, po, pm, pl,
                                                     512, 0, (long)4096 * 1024, 1024, 512, 3);
  fcomb_kernel<8><<<4096, 256, 0, stream>>>(po, pm, pl, attno);
  gemm64_kernel<2><<<dim3(8, 32), 256, 0, stream>>>(attno, wtb + o_cWo, c_bo, lat, 2048, 512, 512, 512, 512);

  for (int i = 0; i < 6; ++i) {
    ln_kernel<<<512, 256, 0, stream>>>(lat, ln1_g + i * 512, ln1_b + i * 512, h, 2048);
    gemm64_kernel<0><<<dim3(24, 32), 256, 0, stream>>>(h, wtb + o_sQKV[i], nullptr, qkv, 2048, 1536, 512, 512, 1536);
    // self attention: 2 KV segments of 128 tokens
    flashsp_kernel<<<dim3(4, 8, 16), 256, 0, stream>>>(qkv, qkv + 512, qkv + 1024, po, pm, pl,
                                                       1536, 256, (long)256 * 1536, 1536, 128, 1);
    fcomb_kernel<2><<<4096, 256, 0, stream>>>(po, pm, pl, attno);
    gemm64_kernel<2><<<dim3(8, 32), 256, 0, stream>>>(attno, wtb + o_sWo[i], s_bo + i * 512, lat, 2048, 512, 512, 512, 512);
    ln_kernel<<<512, 256, 0, stream>>>(lat, ln2_g + i * 512, ln2_b + i * 512, h, 2048);
    gemm64_kernel<1><<<dim3(32, 32), 256, 0, stream>>>(h, wtb + o_fW1[i], f_b1 + i * 2048, ffh, 2048, 2048, 512, 512, 2048);
    gemm64_kernel<2><<<dim3(8, 32), 256, 0, stream>>>(ffh, wtb + o_fW2[i], f_b2 + i * 512, lat, 2048, 512, 2048, 2048, 512);
  }
  ln_kernel<<<512, 256, 0, stream>>>(lat, lnf_g, lnf_b, h, 2048);
  gemm64_kernel<3><<<dim3(1, 32), 256, 0, stream>>>(h, wtb + o_Wb, bbv, outp, 2048, 64, 512, 512, 64);
}